// Round 1
// baseline (66.902 us; speedup 1.0000x reference)
//
#include <hip/hip_runtime.h>
#include <hip/hip_bf16.h>
#include <cstdint>

// Problem: B=32,S=2048,F=16,H=64,E=256.  BS = 65536 rows.
// out[r,e] = sum_f ( mask[r,f] ? mv[f,e] : dot(gelu(x[r,f]*W1[f,:]+b1[f,:]), W2[f,e,:]) + b2[f,e] )
// Restructured as one GEMM: [BS x 1024] x [1024 x 256], with h' = mask?0:gelu(...),
// plus one extra K-step of 32 carrying (mask bits -> mv-b2 rows) and (ones -> sum_f b2).

#define BS_TOTAL 65536
#define F_ 16
#define H_ 64
#define E_ 256
#define BM 128      // rows per block
#define NTHREADS 512

typedef __attribute__((ext_vector_type(8))) short s16x8;   // 8 bf16 (4 VGPRs)
typedef __attribute__((ext_vector_type(4))) float f32x4;   // MFMA acc

// ws layout:
//   [0, 524288)        W2 as bf16, layout [F][E][H] (same as source)
//   [524288, 525312)   sb2[256]  f32 : sum_f b2[f][e]
//   [525312, 541696)   dvals[16][256] f32 : mv[f][e] - b2[f][e]
#define WS_W2_BYTES   (F_ * E_ * H_ * 2)
#define WS_SB2_OFF    WS_W2_BYTES
#define WS_D_OFF      (WS_SB2_OFF + 1024)

__device__ __forceinline__ unsigned short f2bf(float f) {
    unsigned u = __builtin_bit_cast(unsigned, f);
    u += 0x7FFFu + ((u >> 16) & 1u);          // RNE
    return (unsigned short)(u >> 16);
}

// exact-enough gelu (tanh form), abs err ~3e-4:
// gelu(t) = t - t / (1 + exp2(c1*t + c3*t^3))
__device__ __forceinline__ float gelu_f(float t) {
    float t2 = t * t;
    float p  = fmaf(t2, 0.10294324f, 2.3022082f);
    float g2 = p * t;
    float e  = __builtin_amdgcn_exp2f(g2);
    float r  = __builtin_amdgcn_rcpf(1.0f + e);
    return t - t * r;
}

__global__ void prep_w2(const float* __restrict__ W2, unsigned short* __restrict__ W2b) {
    int i = blockIdx.x * 256 + threadIdx.x;     // indexes float4 groups; 262144/4 = 65536
    float4 v = ((const float4*)W2)[i];
    ushort4 o;
    o.x = f2bf(v.x); o.y = f2bf(v.y); o.z = f2bf(v.z); o.w = f2bf(v.w);
    ((ushort4*)W2b)[i] = o;
}

__global__ void prep_bias(const float* __restrict__ b2, const float* __restrict__ mv,
                          float* __restrict__ sb2, float* __restrict__ dvals) {
    int e = threadIdx.x;                        // 256 threads
    float s = 0.f;
    for (int f = 0; f < F_; ++f) {
        float b = b2[f * E_ + e];
        s += b;
        dvals[f * E_ + e] = mv[f * E_ + e] - b;
    }
    sb2[e] = s;
}

__global__ __launch_bounds__(NTHREADS)
void ts_embed_main(const float* __restrict__ x, const int* __restrict__ mask,
                   const float* __restrict__ W1, const float* __restrict__ b1,
                   const unsigned short* __restrict__ W2b,
                   const float* __restrict__ sb2, const float* __restrict__ dvals,
                   float* __restrict__ out) {
    __shared__ __align__(16) short Als[BM * H_];      // [128][64] bf16, swizzled rows
    __shared__ __align__(16) short Bls[E_ * H_];      // [256][64] bf16 (B^T per feature), swizzled
    __shared__ __align__(16) float xs[BM * F_];       // [128][16] f32
    __shared__ __align__(16) float w1s[F_ * H_];
    __shared__ __align__(16) float b1s[F_ * H_];
    __shared__ unsigned mrow[BM];

    const int tid  = threadIdx.x;
    const int lane = tid & 63;
    const int wid  = tid >> 6;       // 0..7
    const int wm   = wid >> 2;       // 0..1
    const int wn   = wid & 3;        // 0..3
    const int rr   = lane & 15;
    const int klo  = (lane >> 4) << 3;   // 0,8,16,24 : k sub-offset of this lane's frag
    const long rowBase = (long)blockIdx.x * BM;

    // ---- stage x tile: 128x16 f32 = 2048 floats = 512 float4
    ((float4*)xs)[tid] = ((const float4*)(x + rowBase * F_))[tid];
    // ---- stage W1/b1 (1024 floats each)
    if (tid < 256)      ((float4*)w1s)[tid]       = ((const float4*)W1)[tid];
    else                ((float4*)b1s)[tid - 256] = ((const float4*)b1)[tid - 256];
    // ---- mask bits per row (mask arrives as int32 0/1)
    if (tid < BM) {
        const int4* mg = (const int4*)(mask + (rowBase + tid) * F_);
        unsigned bits = 0;
        #pragma unroll
        for (int q = 0; q < 4; ++q) {
            int4 m = mg[q];
            bits |= (m.x != 0 ? 1u : 0u) << (q * 4 + 0);
            bits |= (m.y != 0 ? 1u : 0u) << (q * 4 + 1);
            bits |= (m.z != 0 ? 1u : 0u) << (q * 4 + 2);
            bits |= (m.w != 0 ? 1u : 0u) << (q * 4 + 3);
        }
        mrow[tid] = bits;
    }
    __syncthreads();

    f32x4 acc[4][4] = {};

    for (int f = 0; f < F_; ++f) {
        // ---- stage B tile: copy W2b[f] ([256][64] bf16 = 2048 16B-chunks), swizzled
        const s16x8* bsrc = (const s16x8*)(W2b + f * (E_ * H_));
        #pragma unroll
        for (int kq = 0; kq < 4; ++kq) {
            int c = tid + kq * NTHREADS;
            int e = c >> 3, hc = c & 7;
            int byte = (e * 128 + hc * 16) ^ ((e & 7) << 4);
            *(s16x8*)((char*)Bls + byte) = bsrc[c];
        }
        // ---- compute A tile: h' = mask?0:gelu(x*W1+b1), 128x64 -> 1024 16B-chunks
        #pragma unroll
        for (int kq = 0; kq < 2; ++kq) {
            int c = tid + kq * NTHREADS;
            int r = c >> 3, hc = c & 7;
            float xv  = xs[r * F_ + f];
            float sel = ((mrow[r] >> f) & 1u) ? 0.0f : 1.0f;
            float4 w0 = *(const float4*)&w1s[f * H_ + hc * 8];
            float4 w1v = *(const float4*)&w1s[f * H_ + hc * 8 + 4];
            float4 bb0 = *(const float4*)&b1s[f * H_ + hc * 8];
            float4 bb1 = *(const float4*)&b1s[f * H_ + hc * 8 + 4];
            float t[8];
            t[0] = fmaf(xv, w0.x, bb0.x); t[1] = fmaf(xv, w0.y, bb0.y);
            t[2] = fmaf(xv, w0.z, bb0.z); t[3] = fmaf(xv, w0.w, bb0.w);
            t[4] = fmaf(xv, w1v.x, bb1.x); t[5] = fmaf(xv, w1v.y, bb1.y);
            t[6] = fmaf(xv, w1v.z, bb1.z); t[7] = fmaf(xv, w1v.w, bb1.w);
            s16x8 pk;
            #pragma unroll
            for (int j = 0; j < 8; ++j) pk[j] = (short)f2bf(sel * gelu_f(t[j]));
            int byte = (r * 128 + hc * 16) ^ ((r & 7) << 4);
            *(s16x8*)((char*)Als + byte) = pk;
        }
        __syncthreads();

        // ---- MFMA: K=64 for this feature = 2 k-steps of 32
        #pragma unroll
        for (int kk = 0; kk < 2; ++kk) {
            s16x8 af[4], bfr[4];
            #pragma unroll
            for (int m = 0; m < 4; ++m) {
                int r = wm * 64 + m * 16 + rr;
                int byte = (r * 128 + (kk * 32 + klo) * 2) ^ ((r & 7) << 4);
                af[m] = *(const s16x8*)((const char*)Als + byte);
            }
            #pragma unroll
            for (int n = 0; n < 4; ++n) {
                int e = wn * 64 + n * 16 + rr;
                int byte = (e * 128 + (kk * 32 + klo) * 2) ^ ((e & 7) << 4);
                bfr[n] = *(const s16x8*)((const char*)Bls + byte);
            }
            #pragma unroll
            for (int m = 0; m < 4; ++m)
                #pragma unroll
                for (int n = 0; n < 4; ++n)
                    acc[m][n] = __builtin_amdgcn_mfma_f32_16x16x32_bf16(af[m], bfr[n], acc[m][n], 0, 0, 0);
        }
        __syncthreads();
    }

    // ---- tail K-step (k=0..31): A = [mask bits | 1 | 0...], B = [mv-b2 rows | sum b2 | 0...]
    {
        int c = tid;
        #pragma unroll
        for (int kq = 0; kq < 2; ++kq, c += NTHREADS) {
            int e = c >> 2, hc = c & 3;
            s16x8 pk;
            #pragma unroll
            for (int j = 0; j < 8; ++j) {
                int k = hc * 8 + j;
                float v = (k < 16) ? dvals[k * E_ + e] : ((k == 16) ? sb2[e] : 0.0f);
                pk[j] = (short)f2bf(v);
            }
            int byte = (e * 128 + hc * 16) ^ ((e & 7) << 4);
            *(s16x8*)((char*)Bls + byte) = pk;
        }
    }
    {
        int r = tid >> 2, hc = tid & 3;
        unsigned bits = mrow[r];
        s16x8 pk;
        #pragma unroll
        for (int j = 0; j < 8; ++j) {
            int k = hc * 8 + j;
            float v = (k < 16) ? (float)((bits >> k) & 1u) : ((k == 16) ? 1.0f : 0.0f);
            pk[j] = (short)f2bf(v);
        }
        int byte = (r * 128 + hc * 16) ^ ((r & 7) << 4);
        *(s16x8*)((char*)Als + byte) = pk;
    }
    __syncthreads();
    {
        s16x8 af[4], bfr[4];
        #pragma unroll
        for (int m = 0; m < 4; ++m) {
            int r = wm * 64 + m * 16 + rr;
            int byte = (r * 128 + klo * 2) ^ ((r & 7) << 4);
            af[m] = *(const s16x8*)((const char*)Als + byte);
        }
        #pragma unroll
        for (int n = 0; n < 4; ++n) {
            int e = wn * 64 + n * 16 + rr;
            int byte = (e * 128 + klo * 2) ^ ((e & 7) << 4);
            bfr[n] = *(const s16x8*)((const char*)Bls + byte);
        }
        #pragma unroll
        for (int m = 0; m < 4; ++m)
            #pragma unroll
            for (int n = 0; n < 4; ++n)
                acc[m][n] = __builtin_amdgcn_mfma_f32_16x16x32_bf16(af[m], bfr[n], acc[m][n], 0, 0, 0);
    }

    // ---- epilogue: acc holds the full result (bias+mask folded into GEMM)
    const int rg = lane >> 4;
    #pragma unroll
    for (int m = 0; m < 4; ++m) {
        #pragma unroll
        for (int n = 0; n < 4; ++n) {
            int e = wn * 64 + n * 16 + rr;
            long r0 = rowBase + wm * 64 + m * 16 + rg * 4;
            #pragma unroll
            for (int j = 0; j < 4; ++j)
                out[(r0 + j) * E_ + e] = acc[m][n][j];
        }
    }
}

extern "C" void kernel_launch(void* const* d_in, const int* in_sizes, int n_in,
                              void* d_out, int out_size, void* d_ws, size_t ws_size,
                              hipStream_t stream) {
    const float* x    = (const float*)d_in[0];
    const int*   mask = (const int*)d_in[1];
    const float* W1   = (const float*)d_in[2];
    const float* b1   = (const float*)d_in[3];
    const float* W2   = (const float*)d_in[4];
    const float* b2   = (const float*)d_in[5];
    const float* mv   = (const float*)d_in[6];
    float* out = (float*)d_out;

    char* ws = (char*)d_ws;
    unsigned short* W2b = (unsigned short*)ws;
    float* sb2   = (float*)(ws + WS_SB2_OFF);
    float* dvals = (float*)(ws + WS_D_OFF);

    prep_w2<<<dim3(F_ * E_ * H_ / 4 / 256), dim3(256), 0, stream>>>(W2, W2b);
    prep_bias<<<dim3(1), dim3(256), 0, stream>>>(b2, mv, sb2, dvals);
    ts_embed_main<<<dim3(BS_TOTAL / BM), dim3(NTHREADS), 0, stream>>>(
        x, mask, W1, b1, W2b, sb2, dvals, out);
}